// Round 3
// baseline (247.744 us; speedup 1.0000x reference)
//
#include <hip/hip_runtime.h>

// Monotone rational-quadratic spline transform (neural spline flow bin eval).
// inputs [64,4096,128] f32; widths [128,8]; heights [128,8]; derivs [128,9].
// R2 post-mortem: 92us, occupancy 34% (LDS-capped 16 waves/CU), bank
// conflicts = 26% of cycles (group = b^swz was still data-dependent).
// R3: deterministic bank-group layout (group == tid&7 regardless of bin),
// block=512 + launch_bounds(512,8) -> 32 waves/CU, rcp instead of div.

constexpr float TAILF  = 3.0f;
constexpr float EPSF   = 1e-6f;
constexpr int   NB     = 8;
constexpr int   CH     = 128;
constexpr float MIN_BW = 0.01f;
constexpr float MIN_BH = 0.01f;
constexpr float MIN_D  = 0.01f;

// LDS: Par 32KB + edges 2KB = 34KB -> 4 blocks/CU x 8 waves = 32 waves/CU.
__global__ __launch_bounds__(512, 8) void rqs_kernel(
    const float* __restrict__ in,
    const float* __restrict__ widths,
    const float* __restrict__ heights,
    const float* __restrict__ derivs,
    float* __restrict__ out, int n4)
{
    // Record layout: idx(c,b) = ((c>>5)*32 + (c&3)*8 + b)*8 + ((c>>2)&7).
    // idx % 8 == (c>>2)&7 == tid&7 for the owning lanes -> every wave-wide
    // ds_read_b128 hits exactly 8 lanes per bank-group with distinct rows:
    // the 8-cycle pipeline minimum, conflict-free for ANY data-dependent b.
    // A-record at idx: {cwl, 1/bw, delta, d_left}
    // B-record at idx+1024: {bh, dl+dr-2*delta, chl, 0}  (+16384B imm offset)
    __shared__ float4 Par[2048];
    __shared__ float  Eshared[CH * 8]; // interior width-edges cw[1..7] per ch

    const int tid = threadIdx.x;

    // ---- per-block parameter setup: one thread per channel ----
    if (tid < CH) {
        const int c = tid;
        float cwe[NB + 1], che[NB + 1], dv[NB + 1];

        { // widths -> softmax -> affine -> cumsum -> edges in [-3,3]
            float v[NB];
            float m = -3.4e38f;
            for (int k = 0; k < NB; ++k) { v[k] = widths[c * NB + k]; m = fmaxf(m, v[k]); }
            float s = 0.f;
            for (int k = 0; k < NB; ++k) { v[k] = expf(v[k] - m); s += v[k]; }
            float cum = 0.f;
            cwe[0] = 0.f;
            for (int k = 0; k < NB; ++k) {
                float w = (v[k] / s) * (1.0f - MIN_BW * (float)NB) + MIN_BW;
                cum += w;
                cwe[k + 1] = cum;
            }
            float last = fmaxf(cwe[NB], EPSF);
            for (int k = 0; k <= NB; ++k)
                cwe[k] = 2.0f * TAILF * (cwe[k] / last) - TAILF;
        }
        { // heights -> same pipeline
            float v[NB];
            float m = -3.4e38f;
            for (int k = 0; k < NB; ++k) { v[k] = heights[c * NB + k]; m = fmaxf(m, v[k]); }
            float s = 0.f;
            for (int k = 0; k < NB; ++k) { v[k] = expf(v[k] - m); s += v[k]; }
            float cum = 0.f;
            che[0] = 0.f;
            for (int k = 0; k < NB; ++k) {
                float h = (v[k] / s) * (1.0f - MIN_BH * (float)NB) + MIN_BH;
                cum += h;
                che[k + 1] = cum;
            }
            float last = fmaxf(che[NB], EPSF);
            for (int k = 0; k <= NB; ++k)
                che[k] = 2.0f * TAILF * (che[k] / last) - TAILF;
        }
        // derivatives -> stable softplus + MIN_D (matches jax.nn.softplus)
        for (int k = 0; k <= NB; ++k) {
            float x = derivs[c * (NB + 1) + k];
            dv[k] = fmaxf(x, 0.f) + log1pf(expf(-fabsf(x))) + MIN_D;
        }

        const int grp = (c >> 2) & 7;
        const int mb  = ((c >> 5) & 3) * 32 + (c & 3) * 8;
        for (int b = 0; b < NB; ++b) {
            float cwl = cwe[b], cwr = cwe[b + 1];
            float chl = che[b], chr = che[b + 1];
            float bw = cwr - cwl, bh = chr - chl;
            float delta  = bh / bw;
            float inv_bw = 1.0f / bw;
            float dl = dv[b], dr = dv[b + 1];
            float dsum = dl + dr - 2.0f * delta;
            int idx = (mb + b) * 8 + grp;
            Par[idx]        = make_float4(cwl, inv_bw, delta, dl);
            Par[idx + 1024] = make_float4(bh, dsum, chl, 0.f);
        }
        for (int k = 0; k < 7; ++k) Eshared[c * 8 + k] = cwe[k + 1];
        Eshared[c * 8 + 7] = TAILF;
    }
    __syncthreads();

    // Each thread owns 4 fixed channels c0..c0+3 (grid stride is a multiple
    // of 32 float4s) -> 7 search edges per channel live in registers.
    const int l  = tid & 31;
    const int c0 = 4 * l;
    float e[4][7];
    #pragma unroll
    for (int j = 0; j < 4; ++j)
        #pragma unroll
        for (int k = 0; k < 7; ++k)
            e[j][k] = Eshared[(c0 + j) * 8 + k];

    // Per-thread param base (bytes): (l>>3)*4096 + (l&7)*16; per-channel
    // + j*1024 and B-record +16384 fold into ds_read immediate offsets.
    const char* parbase = (const char*)Par + ((l >> 3) * 4096 + (l & 7) * 16);

    const float4* __restrict__ in4  = reinterpret_cast<const float4*>(in);
    float4*       __restrict__ out4 = reinterpret_cast<float4*>(out);
    const int gtid   = blockIdx.x * blockDim.x + tid;
    const int stride = gridDim.x * blockDim.x;

    for (int i = gtid; i < n4; i += stride) {
        float4 x4 = in4[i];
        float xs[4] = {x4.x, x4.y, x4.z, x4.w};
        float r[4];
        #pragma unroll
        for (int j = 0; j < 4; ++j) {
            float xo = xs[j];
            float x  = fminf(fmaxf(xo, -TAILF + EPSF), TAILF - EPSF);
            // edge cw[0] = -TAIL always <= clipped x -> count interior edges
            int b = 0;
            #pragma unroll
            for (int k = 0; k < 7; ++k) b += (x >= e[j][k]) ? 1 : 0;
            const float4* pa = reinterpret_cast<const float4*>(
                parbase + (b << 7) + j * 1024);
            float4 a  = pa[0];      // ds_read offset: j*1024
            float4 bp = pa[1024];   // ds_read offset: j*1024 + 16384
            float theta = (x - a.x) * a.y;          // (x - cwl) / bw
            theta = fminf(fmaxf(theta, 0.f), 1.f);  // v_med3
            float t1m = theta * (1.f - theta);
            float num = bp.x * (a.z * theta * theta + a.w * t1m);
            float den = a.z + bp.y * t1m;
            float res = bp.z + num * __builtin_amdgcn_rcpf(den); // den>0 always
            bool outside = fabsf(xo) > TAILF;
            r[j] = outside ? xo : res;
        }
        out4[i] = make_float4(r[0], r[1], r[2], r[3]);
    }
}

extern "C" void kernel_launch(void* const* d_in, const int* in_sizes, int n_in,
                              void* d_out, int out_size, void* d_ws, size_t ws_size,
                              hipStream_t stream) {
    const float* in      = (const float*)d_in[0];
    const float* widths  = (const float*)d_in[1];
    const float* heights = (const float*)d_in[2];
    const float* derivs  = (const float*)d_in[3];
    float* out = (float*)d_out;

    int n4 = out_size / 4; // 33,554,432 / 4 = 8,388,608
    // 1024 blocks x 512 thr = 4 blocks/CU resident (32 waves/CU), no tail.
    // Grid stride 524288 float4s: multiple of 32 -> fixed channel ownership.
    dim3 grid(1024), block(512);
    hipLaunchKernelGGL(rqs_kernel, grid, block, 0, stream,
                       in, widths, heights, derivs, out, n4);
}

// Round 9
// 244.953 us; speedup vs baseline: 1.0114x; 1.0114x over previous
//
#include <hip/hip_runtime.h>

// Monotone rational-quadratic spline transform (neural spline flow bin eval).
// inputs [64,4096,128] f32; widths [128,8]; heights [128,8]; derivs [128,9].
// R2: 92us @ 16 waves/CU, 26% bank-conflict tax. R3: conflict-free LDS layout
// (1.5e7 -> 5.7e6) but launch_bounds(512,8) forced VGPR=32 -> edge cache
// rematerialized from LDS -> 107us. R7: prefetch-loop variant diverged only
// in the replay phase (call 1 correct) -- unexplained, possibly infra flake;
// reverting to the R2/R3 grid-stride loop (replay-validated twice) and
// keeping launch_bounds(512,4): VGPR cap 128 (expect ~52-64, <=64 keeps
// 32 waves/CU since LDS 36KB caps at 4 blocks/CU).

constexpr float TAILF  = 3.0f;
constexpr float EPSF   = 1e-6f;
constexpr int   NB     = 8;
constexpr int   CH     = 128;
constexpr float MIN_BW = 0.01f;
constexpr float MIN_BH = 0.01f;
constexpr float MIN_D  = 0.01f;

__global__ __launch_bounds__(512, 4) void rqs_kernel(
    const float* __restrict__ in,
    const float* __restrict__ widths,
    const float* __restrict__ heights,
    const float* __restrict__ derivs,
    float* __restrict__ out, int n4)
{
    // Record layout: idx(c,b) = ((c>>5)*32 + (c&3)*8 + b)*8 + ((c>>2)&7).
    // idx % 8 == (c>>2)&7 == lane&7 for the owning lanes -> every wave-wide
    // ds_read_b128 lands exactly 8 lanes per bank-group regardless of the
    // data-dependent bin b: the 8-cycle pipeline minimum, no excess conflicts.
    // A-record at idx:      {cwl, 1/bw, delta, d_left}
    // B-record at idx+1024: {bh, dl+dr-2*delta, chl, 0}   (+16384B imm)
    __shared__ float4 Par[2048];
    __shared__ float  Eshared[CH * 8]; // interior width-edges cw[1..7] per ch

    const int tid = threadIdx.x;

    // ---- per-block parameter setup: one thread per channel ----
    if (tid < CH) {
        const int c = tid;
        float cwe[NB + 1], che[NB + 1], dv[NB + 1];

        { // widths -> softmax -> affine -> cumsum -> edges in [-3,3]
            float v[NB];
            float m = -3.4e38f;
            for (int k = 0; k < NB; ++k) { v[k] = widths[c * NB + k]; m = fmaxf(m, v[k]); }
            float s = 0.f;
            for (int k = 0; k < NB; ++k) { v[k] = expf(v[k] - m); s += v[k]; }
            float cum = 0.f;
            cwe[0] = 0.f;
            for (int k = 0; k < NB; ++k) {
                float w = (v[k] / s) * (1.0f - MIN_BW * (float)NB) + MIN_BW;
                cum += w;
                cwe[k + 1] = cum;
            }
            float last = fmaxf(cwe[NB], EPSF);
            for (int k = 0; k <= NB; ++k)
                cwe[k] = 2.0f * TAILF * (cwe[k] / last) - TAILF;
        }
        { // heights -> same pipeline
            float v[NB];
            float m = -3.4e38f;
            for (int k = 0; k < NB; ++k) { v[k] = heights[c * NB + k]; m = fmaxf(m, v[k]); }
            float s = 0.f;
            for (int k = 0; k < NB; ++k) { v[k] = expf(v[k] - m); s += v[k]; }
            float cum = 0.f;
            che[0] = 0.f;
            for (int k = 0; k < NB; ++k) {
                float h = (v[k] / s) * (1.0f - MIN_BH * (float)NB) + MIN_BH;
                cum += h;
                che[k + 1] = cum;
            }
            float last = fmaxf(che[NB], EPSF);
            for (int k = 0; k <= NB; ++k)
                che[k] = 2.0f * TAILF * (che[k] / last) - TAILF;
        }
        // derivatives -> stable softplus + MIN_D (matches jax.nn.softplus)
        for (int k = 0; k <= NB; ++k) {
            float x = derivs[c * (NB + 1) + k];
            dv[k] = fmaxf(x, 0.f) + log1pf(expf(-fabsf(x))) + MIN_D;
        }

        const int grp = (c >> 2) & 7;
        const int mb  = ((c >> 5) & 3) * 32 + (c & 3) * 8;
        for (int b = 0; b < NB; ++b) {
            float cwl = cwe[b], cwr = cwe[b + 1];
            float chl = che[b], chr = che[b + 1];
            float bw = cwr - cwl, bh = chr - chl;
            float delta  = bh / bw;
            float inv_bw = 1.0f / bw;
            float dl = dv[b], dr = dv[b + 1];
            float dsum = dl + dr - 2.0f * delta;
            int idx = (mb + b) * 8 + grp;
            Par[idx]        = make_float4(cwl, inv_bw, delta, dl);
            Par[idx + 1024] = make_float4(bh, dsum, chl, 0.f);
        }
        for (int k = 0; k < 7; ++k) Eshared[c * 8 + k] = cwe[k + 1];
        Eshared[c * 8 + 7] = TAILF;
    }
    __syncthreads();

    // Each thread owns 4 fixed channels c0..c0+3 (grid stride is a multiple
    // of 32 float4s) -> the 7 search edges per channel live in registers.
    const int l  = tid & 31;
    const int c0 = 4 * l;
    float e[4][7];
    #pragma unroll
    for (int j = 0; j < 4; ++j)
        #pragma unroll
        for (int k = 0; k < 7; ++k)
            e[j][k] = Eshared[(c0 + j) * 8 + k];

    // Per-thread param base (bytes): (l>>3)*4096 + (l&7)*16; per-channel
    // + j*1024 and B-record +16384 fold into ds_read immediate offsets.
    const char* parbase = (const char*)Par + ((l >> 3) * 4096 + (l & 7) * 16);

    const float4* __restrict__ in4  = reinterpret_cast<const float4*>(in);
    float4*       __restrict__ out4 = reinterpret_cast<float4*>(out);
    const int gtid   = blockIdx.x * blockDim.x + tid;
    const int stride = gridDim.x * blockDim.x;

    for (int i = gtid; i < n4; i += stride) {
        float4 x4 = in4[i];
        float xs[4] = {x4.x, x4.y, x4.z, x4.w};
        float r[4];
        #pragma unroll
        for (int j = 0; j < 4; ++j) {
            float xo = xs[j];
            float x  = fminf(fmaxf(xo, -TAILF + EPSF), TAILF - EPSF);
            // edge cw[0] = -TAIL always <= clipped x -> count interior edges
            int b = 0;
            #pragma unroll
            for (int k = 0; k < 7; ++k) b += (x >= e[j][k]) ? 1 : 0;
            const float4* pa = reinterpret_cast<const float4*>(
                parbase + (b << 7) + j * 1024);
            float4 a  = pa[0];      // ds_read imm offset: j*1024
            float4 bp = pa[1024];   // ds_read imm offset: j*1024 + 16384
            float theta = (x - a.x) * a.y;          // (x - cwl) / bw
            theta = fminf(fmaxf(theta, 0.f), 1.f);  // v_med3
            float t1m = theta * (1.f - theta);
            float num = bp.x * (a.z * theta * theta + a.w * t1m);
            float den = a.z + bp.y * t1m;           // always > 0.004
            float res = bp.z + num * __builtin_amdgcn_rcpf(den);
            bool outside = fabsf(xo) > TAILF;
            r[j] = outside ? xo : res;
        }
        out4[i] = make_float4(r[0], r[1], r[2], r[3]);
    }
}

extern "C" void kernel_launch(void* const* d_in, const int* in_sizes, int n_in,
                              void* d_out, int out_size, void* d_ws, size_t ws_size,
                              hipStream_t stream) {
    const float* in      = (const float*)d_in[0];
    const float* widths  = (const float*)d_in[1];
    const float* heights = (const float*)d_in[2];
    const float* derivs  = (const float*)d_in[3];
    float* out = (float*)d_out;

    int n4 = out_size / 4; // 33,554,432 / 4 = 8,388,608
    // 1024 blocks x 512 thr: 4 blocks/CU (LDS-capped) -> 32 waves/CU if
    // VGPR<=64; exactly 16 float4-iters/thread, no tail.
    // Grid stride 524288: multiple of 32 -> fixed channel ownership per lane.
    dim3 grid(1024), block(512);
    hipLaunchKernelGGL(rqs_kernel, grid, block, 0, stream,
                       in, widths, heights, derivs, out, n4);
}

// Round 10
// 243.598 us; speedup vs baseline: 1.0170x; 1.0056x over previous
//
#include <hip/hip_runtime.h>
#include <hip/hip_fp16.h>

// Monotone rational-quadratic spline transform (neural spline flow bin eval).
// inputs [64,4096,128] f32; widths [128,8]; heights [128,8]; derivs [128,9].
// R9 post-mortem: VGPR=32 even with (512,4) -- allocator sinks the edge-cache
// LDS reads into the hot loop (28 ds_read_b32/iter, 32-way conflicted) and the
// 2x b128 param reads put LDS ~2x above the 42us HBM floor. R10:
//  (a) asm-volatile-pin the 28 edge regs (can't be sunk/remat) + (512,8)
//      which caps VGPR at exactly 64 (512-reg file / 8 waves) -> 32 waves/CU.
//  (b) params compressed to ONE 16B record/bin {cwl f32, chl f32,
//      h2(inv_bw,bh), h2(dl,dsum)}, delta=bh*inv_bw -> 1x ds_read_b128/elem.
//  (c) edge preamble at 33-float lane stride: bank=(l+8j+k)%32, conflict-free.

constexpr float TAILF  = 3.0f;
constexpr float EPSF   = 1e-6f;
constexpr int   NB     = 8;
constexpr int   CH     = 128;
constexpr float MIN_BW = 0.01f;
constexpr float MIN_BH = 0.01f;
constexpr float MIN_D  = 0.01f;

__device__ __forceinline__ unsigned pack_h2(float a, float b) {
    unsigned lo = __half_as_ushort(__float2half(a));
    unsigned hi = __half_as_ushort(__float2half(b));
    return (hi << 16) | lo;
}

__global__ __launch_bounds__(512, 8) void rqs_kernel(
    const float* __restrict__ in,
    const float* __restrict__ widths,
    const float* __restrict__ heights,
    const float* __restrict__ derivs,
    float* __restrict__ out, int n4)
{
    // Record layout: idx(c,b) = ((c>>5)*32 + (c&3)*8 + b)*8 + ((c>>2)&7).
    // idx%8 == (c>>2)&7 == lane&7 for the owning lanes -> wave-wide
    // ds_read_b128 lands 8 lanes/bank-group for ANY data-dependent bin b
    // (lane pairs l,l+32 share addresses -> broadcast). 16 KB total.
    __shared__ float4 Par[1024];   // {cwl f32, chl f32, h2(ib,bh), h2(dl,ds)}
    // Edge cache for the preamble only: word addr = l*33 + j*8 + k
    // -> bank (l+8j+k)%32, distinct per lane: zero conflicts.
    __shared__ float E2[33 * 32 + 8];

    const int tid = threadIdx.x;

    // ---- per-block parameter setup: one thread per channel ----
    if (tid < CH) {
        const int c = tid;
        float cwe[NB + 1], che[NB + 1], dv[NB + 1];

        { // widths -> softmax -> affine -> cumsum -> edges in [-3,3]
            float v[NB];
            float m = -3.4e38f;
            for (int k = 0; k < NB; ++k) { v[k] = widths[c * NB + k]; m = fmaxf(m, v[k]); }
            float s = 0.f;
            for (int k = 0; k < NB; ++k) { v[k] = expf(v[k] - m); s += v[k]; }
            float cum = 0.f;
            cwe[0] = 0.f;
            for (int k = 0; k < NB; ++k) {
                float w = (v[k] / s) * (1.0f - MIN_BW * (float)NB) + MIN_BW;
                cum += w;
                cwe[k + 1] = cum;
            }
            float last = fmaxf(cwe[NB], EPSF);
            for (int k = 0; k <= NB; ++k)
                cwe[k] = 2.0f * TAILF * (cwe[k] / last) - TAILF;
        }
        { // heights -> same pipeline
            float v[NB];
            float m = -3.4e38f;
            for (int k = 0; k < NB; ++k) { v[k] = heights[c * NB + k]; m = fmaxf(m, v[k]); }
            float s = 0.f;
            for (int k = 0; k < NB; ++k) { v[k] = expf(v[k] - m); s += v[k]; }
            float cum = 0.f;
            che[0] = 0.f;
            for (int k = 0; k < NB; ++k) {
                float h = (v[k] / s) * (1.0f - MIN_BH * (float)NB) + MIN_BH;
                cum += h;
                che[k + 1] = cum;
            }
            float last = fmaxf(che[NB], EPSF);
            for (int k = 0; k <= NB; ++k)
                che[k] = 2.0f * TAILF * (che[k] / last) - TAILF;
        }
        // derivatives -> stable softplus + MIN_D (matches jax.nn.softplus)
        for (int k = 0; k <= NB; ++k) {
            float x = derivs[c * (NB + 1) + k];
            dv[k] = fmaxf(x, 0.f) + log1pf(expf(-fabsf(x))) + MIN_D;
        }

        const int grp = (c >> 2) & 7;
        const int mb  = ((c >> 5) & 3) * 32 + (c & 3) * 8;
        for (int b = 0; b < NB; ++b) {
            float cwl = cwe[b], cwr = cwe[b + 1];
            float chl = che[b], chr = che[b + 1];
            float bw = cwr - cwl, bh = chr - chl;
            float inv_bw = 1.0f / bw;
            float delta  = bh * inv_bw;
            float dl = dv[b], dr = dv[b + 1];
            float dsum = dl + dr - 2.0f * delta;
            int idx = (mb + b) * 8 + grp;
            Par[idx] = make_float4(cwl, chl,
                                   __uint_as_float(pack_h2(inv_bw, bh)),
                                   __uint_as_float(pack_h2(dl, dsum)));
        }
        // E2[(c>>2)*33 + (c&3)*8 + k] = interior edge k of channel c
        for (int k = 0; k < 7; ++k)
            E2[(c >> 2) * 33 + (c & 3) * 8 + k] = cwe[k + 1];
    }
    __syncthreads();

    // Each thread owns 4 fixed channels c0..c0+3 (grid stride is a multiple
    // of 32 float4s). Load the 28 search edges and PIN them in VGPRs: the
    // volatile asm cannot be sunk into the loop or rematerialized, so the
    // allocator must keep them resident (28 + ~28 working <= 64 cap).
    const int l = tid & 31;
    float e[4][7];
    #pragma unroll
    for (int j = 0; j < 4; ++j)
        #pragma unroll
        for (int k = 0; k < 7; ++k) {
            e[j][k] = E2[l * 33 + j * 8 + k];
            asm volatile("" : "+v"(e[j][k]));
        }

    // Per-thread param base (bytes): (l>>3)*4096 + (l&7)*16; per-channel
    // + j*1024 and bin + b*128 fold into ds_read immediate offsets.
    const char* parbase = (const char*)Par + ((l >> 3) * 4096 + (l & 7) * 16);

    const float4* __restrict__ in4  = reinterpret_cast<const float4*>(in);
    float4*       __restrict__ out4 = reinterpret_cast<float4*>(out);
    const int gtid   = blockIdx.x * blockDim.x + tid;
    const int stride = gridDim.x * blockDim.x;

    for (int i = gtid; i < n4; i += stride) {
        float4 x4 = in4[i];
        float xs[4] = {x4.x, x4.y, x4.z, x4.w};
        float r[4];
        #pragma unroll
        for (int j = 0; j < 4; ++j) {
            float xo = xs[j];
            float x  = fminf(fmaxf(xo, -TAILF + EPSF), TAILF - EPSF);
            // edge cw[0] = -TAIL always <= clipped x -> count interior edges
            int b = 0;
            #pragma unroll
            for (int k = 0; k < 7; ++k) b += (x >= e[j][k]) ? 1 : 0;
            const float4 rec = *reinterpret_cast<const float4*>(
                parbase + (b << 7) + j * 1024);        // one ds_read_b128
            float cwl = rec.x, chl = rec.y;
            unsigned uz = __float_as_uint(rec.z);
            unsigned uw = __float_as_uint(rec.w);
            float inv_bw = __half2float(__ushort_as_half((unsigned short)(uz & 0xffffu)));
            float bh     = __half2float(__ushort_as_half((unsigned short)(uz >> 16)));
            float dl     = __half2float(__ushort_as_half((unsigned short)(uw & 0xffffu)));
            float dsum   = __half2float(__ushort_as_half((unsigned short)(uw >> 16)));
            float delta  = bh * inv_bw;
            float theta  = fminf(fmaxf((x - cwl) * inv_bw, 0.f), 1.f); // v_med3
            float t1m = theta * (1.f - theta);
            float num = bh * (delta * theta * theta + dl * t1m);
            float den = delta + dsum * t1m;            // >= ~0.007 always
            float res = chl + num * __builtin_amdgcn_rcpf(den);
            bool outside = fabsf(xo) > TAILF;
            r[j] = outside ? xo : res;
        }
        out4[i] = make_float4(r[0], r[1], r[2], r[3]);
    }
}

extern "C" void kernel_launch(void* const* d_in, const int* in_sizes, int n_in,
                              void* d_out, int out_size, void* d_ws, size_t ws_size,
                              hipStream_t stream) {
    const float* in      = (const float*)d_in[0];
    const float* widths  = (const float*)d_in[1];
    const float* heights = (const float*)d_in[2];
    const float* derivs  = (const float*)d_in[3];
    float* out = (float*)d_out;

    int n4 = out_size / 4; // 33,554,432 / 4 = 8,388,608
    // 1024 blocks x 512 thr: LDS ~20.6KB, VGPR<=64 -> 4 blocks/CU resident
    // (32 waves/CU), exactly 16 float4-iters/thread, no tail.
    // Grid stride 524288: multiple of 32 -> fixed channel ownership per lane.
    dim3 grid(1024), block(512);
    hipLaunchKernelGGL(rqs_kernel, grid, block, 0, stream,
                       in, widths, heights, derivs, out, n4);
}